// Round 3
// baseline (411.456 us; speedup 1.0000x reference)
//
#include <hip/hip_runtime.h>
#include <hip/hip_bf16.h>

#define NNODES 50000
#define NEDGES 600000
#define NGRAPHS 512
#define BN_EPS 1e-5f

typedef short bf16x8 __attribute__((ext_vector_type(8)));
typedef float f32x4 __attribute__((ext_vector_type(4)));

// split fp32 -> hi/lo bf16 (RNE); hi+lo carries ~16 mantissa bits (weights only)
__device__ __forceinline__ void bf_split(float x, ushort& h, ushort& l) {
    __hip_bfloat16 bh = __float2bfloat16(x);
    float r = x - __bfloat162float(bh);
    __hip_bfloat16 bl = __float2bfloat16(r);
    h = __builtin_bit_cast(ushort, bh);
    l = __builtin_bit_cast(ushort, bl);
}
__device__ __forceinline__ ushort f2b(float x) {
    return __builtin_bit_cast(ushort, __float2bfloat16(x));
}
__device__ __forceinline__ float b2f(ushort u) {
    union { uint i; float f; } c; c.i = ((uint)u) << 16; return c.f;
}

// ------------------------------------------------------------------- prep
// One dispatch: x->bf16 (blocks 0..3124), zero pooled (3125..3316), hist
// over edges (3317..5660; counts pre-zeroed via hipMemsetAsync), wsplit 6
// matrices in MFMA-FRAGMENT ORDER (5661..5756), row_ptr[N] init.
__global__ __launch_bounds__(256) void prep_kernel(
    const float* __restrict__ x, ushort* __restrict__ xh,
    float* __restrict__ pooled, const int* __restrict__ dst,
    int* __restrict__ counts, int* __restrict__ row_ptr,
    const float* W0, const float* W1, const float* W2, const float* W3,
    const float* W4, const float* W5, ushort* __restrict__ hi, ushort* __restrict__ lo) {
    int b = blockIdx.x, t = threadIdx.x;
    if (b < 3125) {                                 // x: 6.4M floats -> bf16
        int f4 = b * 512 + t * 2;
        float4 a0 = ((const float4*)x)[f4];
        float4 a1 = ((const float4*)x)[f4 + 1];
        ushort4 u0 = {f2b(a0.x), f2b(a0.y), f2b(a0.z), f2b(a0.w)};
        ushort4 u1 = {f2b(a1.x), f2b(a1.y), f2b(a1.z), f2b(a1.w)};
        int e0 = f4 * 4;
        *(ushort4*)(xh + e0) = u0;
        *(ushort4*)(xh + e0 + 4) = u1;
        if (b == 0 && t == 0) row_ptr[NNODES] = NEDGES;
    } else if (b < 3317) {                          // pooled: 512*384 floats
        ((float4*)pooled)[(b - 3125) * 256 + t] = make_float4(0.f, 0.f, 0.f, 0.f);
    } else if (b < 5661) {                          // hist: 600000 edges
        int i = (b - 3317) * 256 + t;
        if (i < NEDGES) atomicAdd(&counts[dst[i]], 1);
    } else {                                        // wsplit: 96 blocks
        int wb = b - 5661;
        const float* Ws[6] = {W0, W1, W2, W3, W4, W5};
        const float* W = Ws[wb >> 4];
        ushort* h = hi + (size_t)(wb >> 4) * 16384;
        ushort* l = lo + (size_t)(wb >> 4) * 16384;
        int chunk = wb & 15;
#pragma unroll
        for (int i = 0; i < 4; i++) {
            int idx = chunk * 1024 + i * 256 + t;   // 0..16383 frag-order slot
            int j    = idx & 7;
            int lane = (idx >> 3) & 63;
            int nt   = (idx >> 9) & 7;
            int kb   = (idx >> 12) & 3;
            int k = kb * 32 + ((lane >> 4) << 3) + j;
            int n = nt * 16 + (lane & 15);
            ushort hh, ll;
            bf_split(W[k * 128 + n], hh, ll);
            h[idx] = hh;
            l[idx] = ll;
        }
    }
}

// ---------------------------------------------------------------- CSR build
__global__ __launch_bounds__(256) void scan1_kernel(const int* __restrict__ counts,
                                                    int* __restrict__ partials, int n) {
    __shared__ int s[256];
    int i = blockIdx.x * 256 + threadIdx.x;
    int v = (i < n) ? counts[i] : 0;
    s[threadIdx.x] = v;
    __syncthreads();
    for (int off = 128; off > 0; off >>= 1) {
        if (threadIdx.x < off) s[threadIdx.x] += s[threadIdx.x + off];
        __syncthreads();
    }
    if (threadIdx.x == 0) partials[blockIdx.x] = s[0];
}

// scan3 with inline base reduction (no scan2 dispatch), nb<=256
__global__ __launch_bounds__(256) void scan3_kernel(const int* __restrict__ counts,
                                                    const int* __restrict__ partials,
                                                    int* __restrict__ row_ptr,
                                                    int* __restrict__ cursor, int n, int nb) {
    __shared__ int s[256];
    __shared__ int base_sh;
    int t = threadIdx.x;
    int pv = (t < (int)blockIdx.x && t < nb) ? partials[t] : 0;
    s[t] = pv;
    __syncthreads();
    for (int off = 128; off > 0; off >>= 1) {
        if (t < off) s[t] += s[t + off];
        __syncthreads();
    }
    if (t == 0) base_sh = s[0];
    __syncthreads();
    int base = base_sh;
    int i = blockIdx.x * 256 + t;
    int v = (i < n) ? counts[i] : 0;
    __syncthreads();
    s[t] = v;
    __syncthreads();
    for (int off = 1; off < 256; off <<= 1) {
        int nv = (t >= off) ? s[t - off] : 0;
        __syncthreads();
        s[t] += nv;
        __syncthreads();
    }
    if (i < n) {
        int ex = base + s[t] - v;   // exclusive
        row_ptr[i] = ex;
        cursor[i] = ex;
    }
}

__global__ __launch_bounds__(256) void scatter_kernel(const int* __restrict__ src,
                                                      const int* __restrict__ dst,
                                                      int* __restrict__ cursor,
                                                      int* __restrict__ esrc, int E) {
    int i = blockIdx.x * 256 + threadIdx.x;
    if (i < E) {
        int p = atomicAdd(&cursor[dst[i]], 1);
        esrc[p] = src[i];
    }
}

// 8-edge gather batch, pairwise-tree accumulate (identical order to the
// R14-proven standalone agg kernel -> bitwise-identical numerics).
#define GB8(ACC, E0)                                                            \
    {                                                                           \
        int i0 = esrc[E0],     i1 = esrc[E0 + 1], i2 = esrc[E0 + 2], i3 = esrc[E0 + 3]; \
        int i4 = esrc[E0 + 4], i5 = esrc[E0 + 5], i6 = esrc[E0 + 6], i7 = esrc[E0 + 7]; \
        ushort4 v0 = xv[(size_t)i0 * 32 + q];                                   \
        ushort4 v1 = xv[(size_t)i1 * 32 + q];                                   \
        ushort4 v2 = xv[(size_t)i2 * 32 + q];                                   \
        ushort4 v3 = xv[(size_t)i3 * 32 + q];                                   \
        ushort4 v4 = xv[(size_t)i4 * 32 + q];                                   \
        ushort4 v5 = xv[(size_t)i5 * 32 + q];                                   \
        ushort4 v6 = xv[(size_t)i6 * 32 + q];                                   \
        ushort4 v7 = xv[(size_t)i7 * 32 + q];                                   \
        ACC.x += ((b2f(v0.x) + b2f(v1.x)) + (b2f(v2.x) + b2f(v3.x))) +          \
                 ((b2f(v4.x) + b2f(v5.x)) + (b2f(v6.x) + b2f(v7.x)));           \
        ACC.y += ((b2f(v0.y) + b2f(v1.y)) + (b2f(v2.y) + b2f(v3.y))) +          \
                 ((b2f(v4.y) + b2f(v5.y)) + (b2f(v6.y) + b2f(v7.y)));           \
        ACC.z += ((b2f(v0.z) + b2f(v1.z)) + (b2f(v2.z) + b2f(v3.z))) +          \
                 ((b2f(v4.z) + b2f(v5.z)) + (b2f(v6.z) + b2f(v7.z)));           \
        ACC.w += ((b2f(v0.w) + b2f(v1.w)) + (b2f(v2.w) + b2f(v3.w))) +          \
                 ((b2f(v4.w) + b2f(v5.w)) + (b2f(v6.w) + b2f(v7.w)));           \
    }

// --------------------------------------------------- fused layer (agg + MLP)
// Per block: gather-aggregate 64 node rows (CSR) straight into the LDS
// A-tile (kb-chunk layout A[kb][m][32], same addressing as the proven dbuf),
// then C = act( BN_ReLU( A@W1 ) @ W2 ) with the R14-proven 2-wave 64x64
// tiles, 4x4 frags, fused mean-pool epilogue. Removes the thi plane
// round-trip, 1 dispatch/layer, and lets gather latency overlap other
// blocks' MFMA on the same CU. Aggregation numerics bitwise-identical:
// one 32-lane half-wave per node, 8/2/1 pairwise-tree edge batches; two
// nodes interleaved per half-wave for 16 outstanding gathers (per-node
// order unchanged).
template <bool RELU_OUT, bool WRITE_PLANES>
__global__ __launch_bounds__(128) void layer_kernel(
    const ushort* __restrict__ Pin,
    const int* __restrict__ rp, const int* __restrict__ esrc,
    const ushort* __restrict__ W1hi, const ushort* __restrict__ W1lo,
    const ushort* __restrict__ W2hi, const ushort* __restrict__ W2lo,
    const float* __restrict__ b1, const float* __restrict__ gm,
    const float* __restrict__ bt, const float* __restrict__ rm,
    const float* __restrict__ rv, const float* __restrict__ b2,
    ushort* __restrict__ Ch,
    const int* __restrict__ batch, float* __restrict__ pooled, int poff, int M) {
    __shared__ __align__(16) ushort smem[64 * 136];   // 17408 B (A-chunks then H/P)
    __shared__ int bsm[64];
    const int t = threadIdx.x;            // 0..127
    const int lane = t & 63;
    const int wv = t >> 6;                // col half
    const int row0 = blockIdx.x * 64;
    const int g = lane >> 4, c = lane & 15;

    if (t < 64) bsm[t] = (row0 + t < M) ? batch[row0 + t] : -1;

    // ---------------- fused aggregation -> LDS A[kb][m][32] (bf16)
    {
        const int hw = t >> 5;            // half-wave 0..3: rows hw*16..hw*16+15
        const int q  = t & 31;            // 4 ch per lane
        const ushort4* xv = (const ushort4*)Pin;
        for (int i = 0; i < 16; i += 2) {
            const int mA = hw * 16 + i, mB = mA + 1;
            const int nA = row0 + mA, nB = row0 + mB;
            float4 aA = make_float4(0.f, 0.f, 0.f, 0.f);
            float4 aB = make_float4(0.f, 0.f, 0.f, 0.f);
            int eA = 0, endA = 0, eB = 0, endB = 0;
            if (nA < M) {
                ushort4 s = xv[(size_t)nA * 32 + q];
                aA.x = b2f(s.x); aA.y = b2f(s.y); aA.z = b2f(s.z); aA.w = b2f(s.w);
                eA = rp[nA]; endA = rp[nA + 1];
            }
            if (nB < M) {
                ushort4 s = xv[(size_t)nB * 32 + q];
                aB.x = b2f(s.x); aB.y = b2f(s.y); aB.z = b2f(s.z); aB.w = b2f(s.w);
                eB = rp[nB]; endB = rp[nB + 1];
            }
            // interleaved main: 16 outstanding gathers (A-batch + B-batch)
            while (eA + 8 <= endA && eB + 8 <= endB) {
                int a0 = esrc[eA],     a1 = esrc[eA + 1], a2 = esrc[eA + 2], a3 = esrc[eA + 3];
                int a4 = esrc[eA + 4], a5 = esrc[eA + 5], a6 = esrc[eA + 6], a7 = esrc[eA + 7];
                int b0 = esrc[eB],     b1_ = esrc[eB + 1], b2_ = esrc[eB + 2], b3 = esrc[eB + 3];
                int b4 = esrc[eB + 4], b5 = esrc[eB + 5], b6 = esrc[eB + 6], b7 = esrc[eB + 7];
                ushort4 uA0 = xv[(size_t)a0 * 32 + q], uA1 = xv[(size_t)a1 * 32 + q];
                ushort4 uA2 = xv[(size_t)a2 * 32 + q], uA3 = xv[(size_t)a3 * 32 + q];
                ushort4 uA4 = xv[(size_t)a4 * 32 + q], uA5 = xv[(size_t)a5 * 32 + q];
                ushort4 uA6 = xv[(size_t)a6 * 32 + q], uA7 = xv[(size_t)a7 * 32 + q];
                ushort4 uB0 = xv[(size_t)b0 * 32 + q], uB1 = xv[(size_t)b1_ * 32 + q];
                ushort4 uB2 = xv[(size_t)b2_ * 32 + q], uB3 = xv[(size_t)b3 * 32 + q];
                ushort4 uB4 = xv[(size_t)b4 * 32 + q], uB5 = xv[(size_t)b5 * 32 + q];
                ushort4 uB6 = xv[(size_t)b6 * 32 + q], uB7 = xv[(size_t)b7 * 32 + q];
                aA.x += ((b2f(uA0.x) + b2f(uA1.x)) + (b2f(uA2.x) + b2f(uA3.x))) +
                        ((b2f(uA4.x) + b2f(uA5.x)) + (b2f(uA6.x) + b2f(uA7.x)));
                aA.y += ((b2f(uA0.y) + b2f(uA1.y)) + (b2f(uA2.y) + b2f(uA3.y))) +
                        ((b2f(uA4.y) + b2f(uA5.y)) + (b2f(uA6.y) + b2f(uA7.y)));
                aA.z += ((b2f(uA0.z) + b2f(uA1.z)) + (b2f(uA2.z) + b2f(uA3.z))) +
                        ((b2f(uA4.z) + b2f(uA5.z)) + (b2f(uA6.z) + b2f(uA7.z)));
                aA.w += ((b2f(uA0.w) + b2f(uA1.w)) + (b2f(uA2.w) + b2f(uA3.w))) +
                        ((b2f(uA4.w) + b2f(uA5.w)) + (b2f(uA6.w) + b2f(uA7.w)));
                aB.x += ((b2f(uB0.x) + b2f(uB1.x)) + (b2f(uB2.x) + b2f(uB3.x))) +
                        ((b2f(uB4.x) + b2f(uB5.x)) + (b2f(uB6.x) + b2f(uB7.x)));
                aB.y += ((b2f(uB0.y) + b2f(uB1.y)) + (b2f(uB2.y) + b2f(uB3.y))) +
                        ((b2f(uB4.y) + b2f(uB5.y)) + (b2f(uB6.y) + b2f(uB7.y)));
                aB.z += ((b2f(uB0.z) + b2f(uB1.z)) + (b2f(uB2.z) + b2f(uB3.z))) +
                        ((b2f(uB4.z) + b2f(uB5.z)) + (b2f(uB6.z) + b2f(uB7.z)));
                aB.w += ((b2f(uB0.w) + b2f(uB1.w)) + (b2f(uB2.w) + b2f(uB3.w))) +
                        ((b2f(uB4.w) + b2f(uB5.w)) + (b2f(uB6.w) + b2f(uB7.w)));
                eA += 8; eB += 8;
            }
            // per-node finish: remaining 8-batches, then 2s, then singles
            for (; eA + 8 <= endA; eA += 8) GB8(aA, eA);
            for (; eB + 8 <= endB; eB += 8) GB8(aB, eB);
            for (; eA + 2 <= endA; eA += 2) {
                int i0 = esrc[eA], i1 = esrc[eA + 1];
                ushort4 v0 = xv[(size_t)i0 * 32 + q];
                ushort4 v1 = xv[(size_t)i1 * 32 + q];
                aA.x += b2f(v0.x) + b2f(v1.x); aA.y += b2f(v0.y) + b2f(v1.y);
                aA.z += b2f(v0.z) + b2f(v1.z); aA.w += b2f(v0.w) + b2f(v1.w);
            }
            for (; eA < endA; eA++) {
                ushort4 v = xv[(size_t)esrc[eA] * 32 + q];
                aA.x += b2f(v.x); aA.y += b2f(v.y); aA.z += b2f(v.z); aA.w += b2f(v.w);
            }
            for (; eB + 2 <= endB; eB += 2) {
                int i0 = esrc[eB], i1 = esrc[eB + 1];
                ushort4 v0 = xv[(size_t)i0 * 32 + q];
                ushort4 v1 = xv[(size_t)i1 * 32 + q];
                aB.x += b2f(v0.x) + b2f(v1.x); aB.y += b2f(v0.y) + b2f(v1.y);
                aB.z += b2f(v0.z) + b2f(v1.z); aB.w += b2f(v0.w) + b2f(v1.w);
            }
            for (; eB < endB; eB++) {
                ushort4 v = xv[(size_t)esrc[eB] * 32 + q];
                aB.x += b2f(v.x); aB.y += b2f(v.y); aB.z += b2f(v.z); aB.w += b2f(v.w);
            }
            // bf16 -> LDS A-chunk: ushort index (q>>3)*2048 + m*32 + (q&7)*4
            ushort4 hA = {f2b(aA.x), f2b(aA.y), f2b(aA.z), f2b(aA.w)};
            ushort4 hB = {f2b(aB.x), f2b(aB.y), f2b(aB.z), f2b(aB.w)};
            *(ushort4*)&smem[(q >> 3) * 2048 + mA * 32 + (q & 7) * 4] = hA;
            *(ushort4*)&smem[(q >> 3) * 2048 + mB * 32 + (q & 7) * 4] = hB;
        }
    }
    __syncthreads();

    f32x4 acc[4][4];
#pragma unroll
    for (int i = 0; i < 4; i++)
#pragma unroll
        for (int j = 0; j < 4; j++) acc[i][j] = (f32x4){0.f, 0.f, 0.f, 0.f};

    // ---------------- phase 1: A @ W1 (2 terms); A read-only in LDS, no barriers
    for (int kb = 0; kb < 4; kb++) {
        bf16x8 bh[4], bl[4];
#pragma unroll
        for (int ct = 0; ct < 4; ct++) {
            const size_t wo = (((size_t)kb * 8 + (wv * 4 + ct)) * 64 + lane) * 8;
            bh[ct] = *(const bf16x8*)(W1hi + wo);
            bl[ct] = *(const bf16x8*)(W1lo + wo);
        }
        bf16x8 ah[4];
#pragma unroll
        for (int rt = 0; rt < 4; rt++) {
            int off = kb * 2048 + (rt * 16 + c) * 32 + g * 8;
            ah[rt] = *(bf16x8*)&smem[off];
        }
#pragma unroll
        for (int rt = 0; rt < 4; rt++)
#pragma unroll
            for (int ct = 0; ct < 4; ct++) {
                acc[rt][ct] = __builtin_amdgcn_mfma_f32_16x16x32_bf16(ah[rt], bh[ct], acc[rt][ct], 0, 0, 0);
                acc[rt][ct] = __builtin_amdgcn_mfma_f32_16x16x32_bf16(ah[rt], bl[ct], acc[rt][ct], 0, 0, 0);
            }
    }
    __syncthreads();   // all A reads done -> H may overwrite smem

    // ---------------- BN + ReLU -> H (bf16)
    {
        float cs[4], ca[4];
#pragma unroll
        for (int ct = 0; ct < 4; ct++) {
            int n = wv * 64 + ct * 16 + c;
            float s = gm[n] * rsqrtf(rv[n] + BN_EPS);
            cs[ct] = s;
            ca[ct] = (b1[n] - rm[n]) * s + bt[n];
        }
#pragma unroll
        for (int rt = 0; rt < 4; rt++)
#pragma unroll
            for (int r = 0; r < 4; r++) {
                int row = rt * 16 + g * 4 + r;
#pragma unroll
                for (int ct = 0; ct < 4; ct++) {
                    int col = wv * 64 + ct * 16 + c;
                    float v = fmaxf(acc[rt][ct][r] * cs[ct] + ca[ct], 0.f);
                    smem[row * 136 + col] = f2b(v);
                }
            }
    }
    __syncthreads();

    // ---------------- phase 2: H @ W2 (2 terms)
#pragma unroll
    for (int i = 0; i < 4; i++)
#pragma unroll
        for (int j = 0; j < 4; j++) acc[i][j] = (f32x4){0.f, 0.f, 0.f, 0.f};

    for (int kb = 0; kb < 4; kb++) {
        bf16x8 bh[4], bl[4];
#pragma unroll
        for (int ct = 0; ct < 4; ct++) {
            const size_t wo = (((size_t)kb * 8 + (wv * 4 + ct)) * 64 + lane) * 8;
            bh[ct] = *(const bf16x8*)(W2hi + wo);
            bl[ct] = *(const bf16x8*)(W2lo + wo);
        }
        bf16x8 ah[4];
#pragma unroll
        for (int rt = 0; rt < 4; rt++) {
            int off = (rt * 16 + c) * 136 + kb * 32 + g * 8;
            ah[rt] = *(bf16x8*)&smem[off];
        }
#pragma unroll
        for (int rt = 0; rt < 4; rt++)
#pragma unroll
            for (int ct = 0; ct < 4; ct++) {
                acc[rt][ct] = __builtin_amdgcn_mfma_f32_16x16x32_bf16(ah[rt], bh[ct], acc[rt][ct], 0, 0, 0);
                acc[rt][ct] = __builtin_amdgcn_mfma_f32_16x16x32_bf16(ah[rt], bl[ct], acc[rt][ct], 0, 0, 0);
            }
    }
    __syncthreads();   // all H reads done -> P may overwrite smem

    // ---------------- epilogue: +b2 (,ReLU) -> bf16 plane + LDS P (bf16)
    {
        float ca2[4];
#pragma unroll
        for (int ct = 0; ct < 4; ct++) ca2[ct] = b2[wv * 64 + ct * 16 + c];
#pragma unroll
        for (int rt = 0; rt < 4; rt++)
#pragma unroll
            for (int r = 0; r < 4; r++) {
                int rl = rt * 16 + g * 4 + r;
                int row = row0 + rl;
                bool valid = row < M;
#pragma unroll
                for (int ct = 0; ct < 4; ct++) {
                    int col = wv * 64 + ct * 16 + c;
                    float v = acc[rt][ct][r] + ca2[ct];
                    if (RELU_OUT) v = fmaxf(v, 0.f);
                    ushort hh = f2b(valid ? v : 0.f);
                    smem[rl * 136 + col] = hh;
                    if (WRITE_PLANES && valid) Ch[(size_t)row * 128 + col] = hh;
                }
            }
    }
    __syncthreads();

    // ---------------- fused mean-pool contribution (batch is sorted)
    {
        int col = t;              // 0..127
        int gcur = bsm[0];
        float accp = 0.f;
#pragma unroll 8
        for (int r = 0; r < 64; r++) {
            int gg = bsm[r];
            if (gg != gcur) {     // block-uniform branch (sorted batch)
                if (gcur >= 0) atomicAdd(&pooled[gcur * 384 + poff + col], accp);
                accp = 0.f;
                gcur = gg;
            }
            accp += b2f(smem[r * 136 + col]);
        }
        if (gcur >= 0) atomicAdd(&pooled[gcur * 384 + poff + col], accp);
    }
}

// ------------------------------------------------------------------- final
__global__ __launch_bounds__(128) void final_kernel(const float* __restrict__ pooled,
                                                    const int* __restrict__ batch,
                                                    const float* __restrict__ W,
                                                    const float* __restrict__ b,
                                                    float* __restrict__ out, int n) {
    __shared__ float ps[384];
    int gph = blockIdx.x, t = threadIdx.x;
    int lo1 = 0, hi1 = n;
    while (lo1 < hi1) { int mid = (lo1 + hi1) >> 1; if (batch[mid] < gph) lo1 = mid + 1; else hi1 = mid; }
    int start = lo1;
    int lo2 = start, hi2 = n;
    while (lo2 < hi2) { int mid = (lo2 + hi2) >> 1; if (batch[mid] < gph + 1) lo2 = mid + 1; else hi2 = mid; }
    int cnt = lo2 - start;
    float inv = 1.f / (float)(cnt > 0 ? cnt : 1);
    for (int i = t; i < 384; i += 128) ps[i] = pooled[gph * 384 + i] * inv;
    __syncthreads();
    float acc = b[t];
#pragma unroll 8
    for (int k = 0; k < 384; k++) acc += ps[k] * W[k * 128 + t];
    out[gph * 128 + t] = acc;
}

// ------------------------------------------------------------------ launch
extern "C" void kernel_launch(void* const* d_in, const int* in_sizes, int n_in,
                              void* d_out, int out_size, void* d_ws, size_t ws_size,
                              hipStream_t stream) {
    const float* x     = (const float*)d_in[0];
    const int*   edge  = (const int*)d_in[1];
    const int*   batch = (const int*)d_in[2];
    const float* p[32];
    for (int i = 0; i < n_in && i < 32; i++) p[i] = (const float*)d_in[i];
    const float* lin_W = p[27];
    const float* lin_b = p[28];

    char* w = (char*)d_ws;
    auto alloc = [&](size_t bytes) { void* r = (void*)w; w += (bytes + 255) & ~(size_t)255; return r; };
    const size_t PL = (size_t)NNODES * 128;
    ushort* xh0   = (ushort*)alloc(PL * 2);   // bf16(x); dead after layer-1 gather
    ushort* p1h   = (ushort*)alloc(PL * 2);
    ushort* p2h   = xh0;                      // alias: xh0 dead before layer-2 writes
    float* pooled = (float*)alloc((size_t)NGRAPHS * 384 * 4);
    int* counts   = (int*)alloc((size_t)NNODES * 4);
    int* cursor   = (int*)alloc((size_t)NNODES * 4);
    int* row_ptr  = (int*)alloc((size_t)(NNODES + 1) * 4);
    int* esrc     = (int*)alloc((size_t)NEDGES * 4);
    int* partials = (int*)alloc(256 * 4);
    ushort* wt_hi = (ushort*)alloc((size_t)6 * 16384 * 2);
    ushort* wt_lo = (ushort*)alloc((size_t)6 * 16384 * 2);

    const int* src = edge;
    const int* dst = edge + NEDGES;

    // --- zero counts (stream-ordered), then prep incl. hist + frag wsplit
    hipMemsetAsync(counts, 0, (size_t)NNODES * 4, stream);
    prep_kernel<<<5757, 256, 0, stream>>>(x, xh0, pooled, dst, counts, row_ptr,
                                          p[3], p[9], p[11], p[17], p[19], p[25],
                                          wt_hi, wt_lo);

    // --- CSR build: 3 dispatches (hist folded into prep)
    int nb = (NNODES + 255) / 256;  // 196
    scan1_kernel<<<nb, 256, 0, stream>>>(counts, partials, NNODES);
    scan3_kernel<<<nb, 256, 0, stream>>>(counts, partials, row_ptr, cursor, NNODES, nb);
    scatter_kernel<<<(NEDGES + 255) / 256, 256, 0, stream>>>(src, dst, cursor, esrc, NEDGES);

    // --- 3 fused GIN layers (agg + MLP + mean-pool contribution)
    int grid = (NNODES + 63) / 64;              // 782
    layer_kernel<true, true><<<grid, 128, 0, stream>>>(xh0, row_ptr, esrc,
        wt_hi + 0 * 16384, wt_lo + 0 * 16384, wt_hi + 1 * 16384, wt_lo + 1 * 16384,
        p[4], p[5], p[6], p[7], p[8], p[10], p1h, batch, pooled, 0, NNODES);
    layer_kernel<true, true><<<grid, 128, 0, stream>>>(p1h, row_ptr, esrc,
        wt_hi + 2 * 16384, wt_lo + 2 * 16384, wt_hi + 3 * 16384, wt_lo + 3 * 16384,
        p[12], p[13], p[14], p[15], p[16], p[18], p2h, batch, pooled, 128, NNODES);
    layer_kernel<false, false><<<grid, 128, 0, stream>>>(p2h, row_ptr, esrc,
        wt_hi + 4 * 16384, wt_lo + 4 * 16384, wt_hi + 5 * 16384, wt_lo + 5 * 16384,
        p[20], p[21], p[22], p[23], p[24], p[26], nullptr, batch, pooled, 256, NNODES);

    // --- final linear on mean-pooled JK-concat
    final_kernel<<<NGRAPHS, 128, 0, stream>>>(pooled, batch, lin_W, lin_b,
                                              (float*)d_out, NNODES);
}

// Round 4
// 340.948 us; speedup vs baseline: 1.2068x; 1.2068x over previous
//
#include <hip/hip_runtime.h>
#include <hip/hip_bf16.h>

#define NNODES 50000
#define NEDGES 600000
#define NGRAPHS 512
#define BN_EPS 1e-5f

typedef short bf16x8 __attribute__((ext_vector_type(8)));
typedef float f32x4 __attribute__((ext_vector_type(4)));

// split fp32 -> hi/lo bf16 (RNE); hi+lo carries ~16 mantissa bits (weights only)
__device__ __forceinline__ void bf_split(float x, ushort& h, ushort& l) {
    __hip_bfloat16 bh = __float2bfloat16(x);
    float r = x - __bfloat162float(bh);
    __hip_bfloat16 bl = __float2bfloat16(r);
    h = __builtin_bit_cast(ushort, bh);
    l = __builtin_bit_cast(ushort, bl);
}
__device__ __forceinline__ ushort f2b(float x) {
    return __builtin_bit_cast(ushort, __float2bfloat16(x));
}
__device__ __forceinline__ float b2f(ushort u) {
    union { uint i; float f; } c; c.i = ((uint)u) << 16; return c.f;
}
// bf16 pair unpack from a packed uint: lo = shift, hi = mask (1 VALU each)
__device__ __forceinline__ float blo(uint u) {
    union { uint i; float f; } c; c.i = u << 16; return c.f;
}
__device__ __forceinline__ float bhi(uint u) {
    union { uint i; float f; } c; c.i = u & 0xffff0000u; return c.f;
}

// ------------------------------------------------------------------- prep
// One dispatch: x->bf16 (blocks 0..3124), zero pooled (3125..3316), hist
// over edges (3317..5660; counts pre-zeroed via hipMemsetAsync), wsplit 6
// matrices in MFMA-FRAGMENT ORDER (5661..5756), row_ptr[N] init.
__global__ __launch_bounds__(256) void prep_kernel(
    const float* __restrict__ x, ushort* __restrict__ xh,
    float* __restrict__ pooled, const int* __restrict__ dst,
    int* __restrict__ counts, int* __restrict__ row_ptr,
    const float* W0, const float* W1, const float* W2, const float* W3,
    const float* W4, const float* W5, ushort* __restrict__ hi, ushort* __restrict__ lo) {
    int b = blockIdx.x, t = threadIdx.x;
    if (b < 3125) {                                 // x: 6.4M floats -> bf16
        int f4 = b * 512 + t * 2;
        float4 a0 = ((const float4*)x)[f4];
        float4 a1 = ((const float4*)x)[f4 + 1];
        ushort4 u0 = {f2b(a0.x), f2b(a0.y), f2b(a0.z), f2b(a0.w)};
        ushort4 u1 = {f2b(a1.x), f2b(a1.y), f2b(a1.z), f2b(a1.w)};
        int e0 = f4 * 4;
        *(ushort4*)(xh + e0) = u0;
        *(ushort4*)(xh + e0 + 4) = u1;
        if (b == 0 && t == 0) row_ptr[NNODES] = NEDGES;
    } else if (b < 3317) {                          // pooled: 512*384 floats
        ((float4*)pooled)[(b - 3125) * 256 + t] = make_float4(0.f, 0.f, 0.f, 0.f);
    } else if (b < 5661) {                          // hist: 600000 edges
        int i = (b - 3317) * 256 + t;
        if (i < NEDGES) atomicAdd(&counts[dst[i]], 1);
    } else {                                        // wsplit: 96 blocks
        int wb = b - 5661;
        const float* Ws[6] = {W0, W1, W2, W3, W4, W5};
        const float* W = Ws[wb >> 4];
        ushort* h = hi + (size_t)(wb >> 4) * 16384;
        ushort* l = lo + (size_t)(wb >> 4) * 16384;
        int chunk = wb & 15;
#pragma unroll
        for (int i = 0; i < 4; i++) {
            int idx = chunk * 1024 + i * 256 + t;   // 0..16383 frag-order slot
            int j    = idx & 7;
            int lane = (idx >> 3) & 63;
            int nt   = (idx >> 9) & 7;
            int kb   = (idx >> 12) & 3;
            int k = kb * 32 + ((lane >> 4) << 3) + j;
            int n = nt * 16 + (lane & 15);
            ushort hh, ll;
            bf_split(W[k * 128 + n], hh, ll);
            h[idx] = hh;
            l[idx] = ll;
        }
    }
}

// ---------------------------------------------------------------- CSR build
__global__ __launch_bounds__(256) void scan1_kernel(const int* __restrict__ counts,
                                                    int* __restrict__ partials, int n) {
    __shared__ int s[256];
    int i = blockIdx.x * 256 + threadIdx.x;
    int v = (i < n) ? counts[i] : 0;
    s[threadIdx.x] = v;
    __syncthreads();
    for (int off = 128; off > 0; off >>= 1) {
        if (threadIdx.x < off) s[threadIdx.x] += s[threadIdx.x + off];
        __syncthreads();
    }
    if (threadIdx.x == 0) partials[blockIdx.x] = s[0];
}

// scan3 with inline base reduction (no scan2 dispatch), nb<=256
__global__ __launch_bounds__(256) void scan3_kernel(const int* __restrict__ counts,
                                                    const int* __restrict__ partials,
                                                    int* __restrict__ row_ptr,
                                                    int* __restrict__ cursor, int n, int nb) {
    __shared__ int s[256];
    __shared__ int base_sh;
    int t = threadIdx.x;
    int pv = (t < (int)blockIdx.x && t < nb) ? partials[t] : 0;
    s[t] = pv;
    __syncthreads();
    for (int off = 128; off > 0; off >>= 1) {
        if (t < off) s[t] += s[t + off];
        __syncthreads();
    }
    if (t == 0) base_sh = s[0];
    __syncthreads();
    int base = base_sh;
    int i = blockIdx.x * 256 + t;
    int v = (i < n) ? counts[i] : 0;
    __syncthreads();
    s[t] = v;
    __syncthreads();
    for (int off = 1; off < 256; off <<= 1) {
        int nv = (t >= off) ? s[t - off] : 0;
        __syncthreads();
        s[t] += nv;
        __syncthreads();
    }
    if (i < n) {
        int ex = base + s[t] - v;   // exclusive
        row_ptr[i] = ex;
        cursor[i] = ex;
    }
}

__global__ __launch_bounds__(256) void scatter_kernel(const int* __restrict__ src,
                                                      const int* __restrict__ dst,
                                                      int* __restrict__ cursor,
                                                      int* __restrict__ esrc, int E) {
    int i = blockIdx.x * 256 + threadIdx.x;
    if (i < E) {
        int p = atomicAdd(&cursor[dst[i]], 1);
        esrc[p] = src[i];
    }
}

// ------------------------------------------------------------- aggregation
// R4: 4 nodes/wave, 16 lanes x 8 ch (uint4 = 16B/lane). Same bytes as the
// R14-proven 2-node version but HALF the load instructions + address VALU,
// 2x bytes in flight per wave. Per-channel accumulation order unchanged
// (8/2/1 pairwise tree) -> bitwise-identical output. hi-channel unpack is
// a 1-VALU mask; lo a 1-VALU shift. fp32 accumulate -> bf16 plane out.
__global__ __launch_bounds__(256) void agg_kernel(
    const ushort* __restrict__ phi,
    const int* __restrict__ rp, const int* __restrict__ esrc,
    ushort* __restrict__ ohi, int n) {
    int wid  = (blockIdx.x * 256 + threadIdx.x) >> 6;
    int lane = threadIdx.x & 63;
    int node = wid * 4 + (lane >> 4);
    int q = lane & 15;                   // 16B granule: channels q*8..q*8+7
    if (node >= n) return;
    const uint4* xv = (const uint4*)phi; // row = 16 granules of 16B
    uint4 s0 = xv[(size_t)node * 16 + q];
    float acc[8];
    acc[0] = blo(s0.x); acc[1] = bhi(s0.x);
    acc[2] = blo(s0.y); acc[3] = bhi(s0.y);
    acc[4] = blo(s0.z); acc[5] = bhi(s0.z);
    acc[6] = blo(s0.w); acc[7] = bhi(s0.w);
    int e = rp[node], end = rp[node + 1];
    for (; e + 8 <= end; e += 8) {
        int i0 = esrc[e],     i1 = esrc[e + 1], i2 = esrc[e + 2], i3 = esrc[e + 3];
        int i4 = esrc[e + 4], i5 = esrc[e + 5], i6 = esrc[e + 6], i7 = esrc[e + 7];
        uint4 v0 = xv[(size_t)i0 * 16 + q];
        uint4 v1 = xv[(size_t)i1 * 16 + q];
        uint4 v2 = xv[(size_t)i2 * 16 + q];
        uint4 v3 = xv[(size_t)i3 * 16 + q];
        uint4 v4 = xv[(size_t)i4 * 16 + q];
        uint4 v5 = xv[(size_t)i5 * 16 + q];
        uint4 v6 = xv[(size_t)i6 * 16 + q];
        uint4 v7 = xv[(size_t)i7 * 16 + q];
        acc[0] += ((blo(v0.x) + blo(v1.x)) + (blo(v2.x) + blo(v3.x))) +
                  ((blo(v4.x) + blo(v5.x)) + (blo(v6.x) + blo(v7.x)));
        acc[1] += ((bhi(v0.x) + bhi(v1.x)) + (bhi(v2.x) + bhi(v3.x))) +
                  ((bhi(v4.x) + bhi(v5.x)) + (bhi(v6.x) + bhi(v7.x)));
        acc[2] += ((blo(v0.y) + blo(v1.y)) + (blo(v2.y) + blo(v3.y))) +
                  ((blo(v4.y) + blo(v5.y)) + (blo(v6.y) + blo(v7.y)));
        acc[3] += ((bhi(v0.y) + bhi(v1.y)) + (bhi(v2.y) + bhi(v3.y))) +
                  ((bhi(v4.y) + bhi(v5.y)) + (bhi(v6.y) + bhi(v7.y)));
        acc[4] += ((blo(v0.z) + blo(v1.z)) + (blo(v2.z) + blo(v3.z))) +
                  ((blo(v4.z) + blo(v5.z)) + (blo(v6.z) + blo(v7.z)));
        acc[5] += ((bhi(v0.z) + bhi(v1.z)) + (bhi(v2.z) + bhi(v3.z))) +
                  ((bhi(v4.z) + bhi(v5.z)) + (bhi(v6.z) + bhi(v7.z)));
        acc[6] += ((blo(v0.w) + blo(v1.w)) + (blo(v2.w) + blo(v3.w))) +
                  ((blo(v4.w) + blo(v5.w)) + (blo(v6.w) + blo(v7.w)));
        acc[7] += ((bhi(v0.w) + bhi(v1.w)) + (bhi(v2.w) + bhi(v3.w))) +
                  ((bhi(v4.w) + bhi(v5.w)) + (bhi(v6.w) + bhi(v7.w)));
    }
    for (; e + 2 <= end; e += 2) {
        int i0 = esrc[e], i1 = esrc[e + 1];
        uint4 v0 = xv[(size_t)i0 * 16 + q];
        uint4 v1 = xv[(size_t)i1 * 16 + q];
        acc[0] += blo(v0.x) + blo(v1.x); acc[1] += bhi(v0.x) + bhi(v1.x);
        acc[2] += blo(v0.y) + blo(v1.y); acc[3] += bhi(v0.y) + bhi(v1.y);
        acc[4] += blo(v0.z) + blo(v1.z); acc[5] += bhi(v0.z) + bhi(v1.z);
        acc[6] += blo(v0.w) + blo(v1.w); acc[7] += bhi(v0.w) + bhi(v1.w);
    }
    for (; e < end; e++) {
        uint4 v = xv[(size_t)esrc[e] * 16 + q];
        acc[0] += blo(v.x); acc[1] += bhi(v.x);
        acc[2] += blo(v.y); acc[3] += bhi(v.y);
        acc[4] += blo(v.z); acc[5] += bhi(v.z);
        acc[6] += blo(v.w); acc[7] += bhi(v.w);
    }
    uint4 o;
    o.x = (uint)f2b(acc[0]) | ((uint)f2b(acc[1]) << 16);
    o.y = (uint)f2b(acc[2]) | ((uint)f2b(acc[3]) << 16);
    o.z = (uint)f2b(acc[4]) | ((uint)f2b(acc[5]) << 16);
    o.w = (uint)f2b(acc[6]) | ((uint)f2b(acc[7]) << 16);
    *(uint4*)(ohi + (size_t)node * 128 + q * 8) = o;
}

// --------------------------------------------------------------- fused MLP
// C = act( BN_ReLU( A@W1 ) @ W2 ), 64-row tile x 128 threads (2 waves).
// PER-WAVE SHAPE UNCHANGED from proven R14: 64x64 wave tile, 4x4 frags,
// 32 MFMA/kb. W planes stored in MFMA-fragment order -> each bh/bl load is
// one coalesced contiguous 1KB wave transaction. Fused mean-pool epilogue.
template <bool RELU_OUT, bool WRITE_PLANES>
__global__ __launch_bounds__(128) void mlp_kernel(
    const ushort* __restrict__ Ah,
    const ushort* __restrict__ W1hi, const ushort* __restrict__ W1lo,
    const ushort* __restrict__ W2hi, const ushort* __restrict__ W2lo,
    const float* __restrict__ b1, const float* __restrict__ gm,
    const float* __restrict__ bt, const float* __restrict__ rm,
    const float* __restrict__ rv, const float* __restrict__ b2,
    ushort* __restrict__ Ch,
    const int* __restrict__ batch, float* __restrict__ pooled, int poff, int M) {
    __shared__ __align__(16) ushort smem[64 * 136];   // 17408 B
    __shared__ int bsm[64];
    // A dbuf: smem[buf*4096 + m*32 + k]  (8192 ushorts, fits in smem)
    // H / P:  smem[row*136 + col]
    const int t = threadIdx.x;            // 0..127
    const int lane = t & 63;
    const int wv = t >> 6;                // col half
    const int row0 = blockIdx.x * 64;
    const int g = lane >> 4, c = lane & 15;

    if (t < 64) bsm[t] = (row0 + t < M) ? batch[row0 + t] : -1;

    // staging: 256 16B-segs per kb; thread owns segs t and t+128
    const int m0 = t >> 2, k80 = (t & 3) * 8;
    const int m1 = m0 + 32;
    int r0 = row0 + m0; if (r0 >= M) r0 = M - 1;
    int r1 = row0 + m1; if (r1 >= M) r1 = M - 1;
    const size_t ga0 = (size_t)r0 * 128 + k80;
    const size_t ga1 = (size_t)r1 * 128 + k80;
    const int la0 = m0 * 32 + k80, la1 = m1 * 32 + k80;

    f32x4 acc[4][4];
#pragma unroll
    for (int i = 0; i < 4; i++)
#pragma unroll
        for (int j = 0; j < 4; j++) acc[i][j] = (f32x4){0.f, 0.f, 0.f, 0.f};

    uint4 ph0 = *(const uint4*)(Ah + ga0);
    uint4 ph1 = *(const uint4*)(Ah + ga1);
    *(uint4*)&smem[la0] = ph0;
    *(uint4*)&smem[la1] = ph1;
    __syncthreads();

    // ---------------- phase 1: A @ W1 (2 terms)
    int cur = 0;
    for (int kb = 0; kb < 4; kb++) {
        bf16x8 bh[4], bl[4];
#pragma unroll
        for (int ct = 0; ct < 4; ct++) {
            const size_t wo = (((size_t)kb * 8 + (wv * 4 + ct)) * 64 + lane) * 8;
            bh[ct] = *(const bf16x8*)(W1hi + wo);
            bl[ct] = *(const bf16x8*)(W1lo + wo);
        }
        if (kb < 3) {
            const size_t o = (size_t)(kb + 1) * 32;
            ph0 = *(const uint4*)(Ah + ga0 + o);
            ph1 = *(const uint4*)(Ah + ga1 + o);
        }
        bf16x8 ah[4];
#pragma unroll
        for (int rt = 0; rt < 4; rt++) {
            int off = cur * 4096 + (rt * 16 + c) * 32 + g * 8;
            ah[rt] = *(bf16x8*)&smem[off];
        }
#pragma unroll
        for (int rt = 0; rt < 4; rt++)
#pragma unroll
            for (int ct = 0; ct < 4; ct++) {
                acc[rt][ct] = __builtin_amdgcn_mfma_f32_16x16x32_bf16(ah[rt], bh[ct], acc[rt][ct], 0, 0, 0);
                acc[rt][ct] = __builtin_amdgcn_mfma_f32_16x16x32_bf16(ah[rt], bl[ct], acc[rt][ct], 0, 0, 0);
            }
        if (kb < 3) {
            *(uint4*)&smem[(cur ^ 1) * 4096 + la0] = ph0;
            *(uint4*)&smem[(cur ^ 1) * 4096 + la1] = ph1;
        }
        __syncthreads();   // final iter: all A reads done -> H may overwrite
        cur ^= 1;
    }

    // ---------------- BN + ReLU -> H (bf16)
    {
        float cs[4], ca[4];
#pragma unroll
        for (int ct = 0; ct < 4; ct++) {
            int n = wv * 64 + ct * 16 + c;
            float s = gm[n] * rsqrtf(rv[n] + BN_EPS);
            cs[ct] = s;
            ca[ct] = (b1[n] - rm[n]) * s + bt[n];
        }
#pragma unroll
        for (int rt = 0; rt < 4; rt++)
#pragma unroll
            for (int r = 0; r < 4; r++) {
                int row = rt * 16 + g * 4 + r;
#pragma unroll
                for (int ct = 0; ct < 4; ct++) {
                    int col = wv * 64 + ct * 16 + c;
                    float v = fmaxf(acc[rt][ct][r] * cs[ct] + ca[ct], 0.f);
                    smem[row * 136 + col] = f2b(v);
                }
            }
    }
    __syncthreads();

    // ---------------- phase 2: H @ W2 (2 terms)
#pragma unroll
    for (int i = 0; i < 4; i++)
#pragma unroll
        for (int j = 0; j < 4; j++) acc[i][j] = (f32x4){0.f, 0.f, 0.f, 0.f};

    for (int kb = 0; kb < 4; kb++) {
        bf16x8 bh[4], bl[4];
#pragma unroll
        for (int ct = 0; ct < 4; ct++) {
            const size_t wo = (((size_t)kb * 8 + (wv * 4 + ct)) * 64 + lane) * 8;
            bh[ct] = *(const bf16x8*)(W2hi + wo);
            bl[ct] = *(const bf16x8*)(W2lo + wo);
        }
        bf16x8 ah[4];
#pragma unroll
        for (int rt = 0; rt < 4; rt++) {
            int off = (rt * 16 + c) * 136 + kb * 32 + g * 8;
            ah[rt] = *(bf16x8*)&smem[off];
        }
#pragma unroll
        for (int rt = 0; rt < 4; rt++)
#pragma unroll
            for (int ct = 0; ct < 4; ct++) {
                acc[rt][ct] = __builtin_amdgcn_mfma_f32_16x16x32_bf16(ah[rt], bh[ct], acc[rt][ct], 0, 0, 0);
                acc[rt][ct] = __builtin_amdgcn_mfma_f32_16x16x32_bf16(ah[rt], bl[ct], acc[rt][ct], 0, 0, 0);
            }
    }
    __syncthreads();   // all H reads done -> P may overwrite smem

    // ---------------- epilogue: +b2 (,ReLU) -> bf16 plane + LDS P (bf16)
    {
        float ca2[4];
#pragma unroll
        for (int ct = 0; ct < 4; ct++) ca2[ct] = b2[wv * 64 + ct * 16 + c];
#pragma unroll
        for (int rt = 0; rt < 4; rt++)
#pragma unroll
            for (int r = 0; r < 4; r++) {
                int rl = rt * 16 + g * 4 + r;
                int row = row0 + rl;
                bool valid = row < M;
#pragma unroll
                for (int ct = 0; ct < 4; ct++) {
                    int col = wv * 64 + ct * 16 + c;
                    float v = acc[rt][ct][r] + ca2[ct];
                    if (RELU_OUT) v = fmaxf(v, 0.f);
                    ushort hh = f2b(valid ? v : 0.f);
                    smem[rl * 136 + col] = hh;
                    if (WRITE_PLANES && valid) Ch[(size_t)row * 128 + col] = hh;
                }
            }
    }
    __syncthreads();

    // ---------------- fused mean-pool contribution (batch is sorted)
    {
        int col = t;              // 0..127
        int gcur = bsm[0];
        float accp = 0.f;
#pragma unroll 8
        for (int r = 0; r < 64; r++) {
            int gg = bsm[r];
            if (gg != gcur) {     // block-uniform branch (sorted batch)
                if (gcur >= 0) atomicAdd(&pooled[gcur * 384 + poff + col], accp);
                accp = 0.f;
                gcur = gg;
            }
            accp += b2f(smem[r * 136 + col]);
        }
        if (gcur >= 0) atomicAdd(&pooled[gcur * 384 + poff + col], accp);
    }
}

// ------------------------------------------------------------------- final
__global__ __launch_bounds__(128) void final_kernel(const float* __restrict__ pooled,
                                                    const int* __restrict__ batch,
                                                    const float* __restrict__ W,
                                                    const float* __restrict__ b,
                                                    float* __restrict__ out, int n) {
    __shared__ float ps[384];
    int gph = blockIdx.x, t = threadIdx.x;
    int lo1 = 0, hi1 = n;
    while (lo1 < hi1) { int mid = (lo1 + hi1) >> 1; if (batch[mid] < gph) lo1 = mid + 1; else hi1 = mid; }
    int start = lo1;
    int lo2 = start, hi2 = n;
    while (lo2 < hi2) { int mid = (lo2 + hi2) >> 1; if (batch[mid] < gph + 1) lo2 = mid + 1; else hi2 = mid; }
    int cnt = lo2 - start;
    float inv = 1.f / (float)(cnt > 0 ? cnt : 1);
    for (int i = t; i < 384; i += 128) ps[i] = pooled[gph * 384 + i] * inv;
    __syncthreads();
    float acc = b[t];
#pragma unroll 8
    for (int k = 0; k < 384; k++) acc += ps[k] * W[k * 128 + t];
    out[gph * 128 + t] = acc;
}

// ------------------------------------------------------------------ launch
extern "C" void kernel_launch(void* const* d_in, const int* in_sizes, int n_in,
                              void* d_out, int out_size, void* d_ws, size_t ws_size,
                              hipStream_t stream) {
    const float* x     = (const float*)d_in[0];
    const int*   edge  = (const int*)d_in[1];
    const int*   batch = (const int*)d_in[2];
    const float* p[32];
    for (int i = 0; i < n_in && i < 32; i++) p[i] = (const float*)d_in[i];
    const float* lin_W = p[27];
    const float* lin_b = p[28];

    char* w = (char*)d_ws;
    auto alloc = [&](size_t bytes) { void* r = (void*)w; w += (bytes + 255) & ~(size_t)255; return r; };
    const size_t PL = (size_t)NNODES * 128;
    ushort* thi   = (ushort*)alloc(PL * 2);   // agg out plane
    ushort* xh0   = (ushort*)alloc(PL * 2);   // bf16(x); dead after agg L1
    ushort* p1h   = (ushort*)alloc(PL * 2);
    ushort* p2h   = xh0;                      // alias: xh0 dead before mlp L2 writes
    float* pooled = (float*)alloc((size_t)NGRAPHS * 384 * 4);
    int* counts   = (int*)alloc((size_t)NNODES * 4);
    int* cursor   = (int*)alloc((size_t)NNODES * 4);
    int* row_ptr  = (int*)alloc((size_t)(NNODES + 1) * 4);
    int* esrc     = (int*)alloc((size_t)NEDGES * 4);
    int* partials = (int*)alloc(256 * 4);
    ushort* wt_hi = (ushort*)alloc((size_t)6 * 16384 * 2);
    ushort* wt_lo = (ushort*)alloc((size_t)6 * 16384 * 2);

    const int* src = edge;
    const int* dst = edge + NEDGES;

    // --- zero counts (stream-ordered), then prep incl. hist + frag wsplit
    hipMemsetAsync(counts, 0, (size_t)NNODES * 4, stream);
    prep_kernel<<<5757, 256, 0, stream>>>(x, xh0, pooled, dst, counts, row_ptr,
                                          p[3], p[9], p[11], p[17], p[19], p[25],
                                          wt_hi, wt_lo);

    // --- CSR build: 3 dispatches (hist folded into prep)
    int nb = (NNODES + 255) / 256;  // 196
    scan1_kernel<<<nb, 256, 0, stream>>>(counts, partials, NNODES);
    scan3_kernel<<<nb, 256, 0, stream>>>(counts, partials, row_ptr, cursor, NNODES, nb);
    scatter_kernel<<<(NEDGES + 255) / 256, 256, 0, stream>>>(src, dst, cursor, esrc, NEDGES);

    // --- 3 GIN layers (mlp fuses the mean-pool contribution)
    int mlp_grid = (NNODES + 63) / 64;              // 782
    int agg_grid = (NNODES / 4 * 64 + 255) / 256;   // 3125

    // layer 1 (self from bf16 plane — same rounding class as neighbors)
    agg_kernel<<<agg_grid, 256, 0, stream>>>(xh0, row_ptr, esrc, thi, NNODES);
    mlp_kernel<true, true><<<mlp_grid, 128, 0, stream>>>(thi,
        wt_hi + 0 * 16384, wt_lo + 0 * 16384, wt_hi + 1 * 16384, wt_lo + 1 * 16384,
        p[4], p[5], p[6], p[7], p[8], p[10], p1h, batch, pooled, 0, NNODES);
    // layer 2
    agg_kernel<<<agg_grid, 256, 0, stream>>>(p1h, row_ptr, esrc, thi, NNODES);
    mlp_kernel<true, true><<<mlp_grid, 128, 0, stream>>>(thi,
        wt_hi + 2 * 16384, wt_lo + 2 * 16384, wt_hi + 3 * 16384, wt_lo + 3 * 16384,
        p[12], p[13], p[14], p[15], p[16], p[18], p2h, batch, pooled, 128, NNODES);
    // layer 3 (no relu, no plane writes — pool-only output)
    agg_kernel<<<agg_grid, 256, 0, stream>>>(p2h, row_ptr, esrc, thi, NNODES);
    mlp_kernel<false, false><<<mlp_grid, 128, 0, stream>>>(thi,
        wt_hi + 4 * 16384, wt_lo + 4 * 16384, wt_hi + 5 * 16384, wt_lo + 5 * 16384,
        p[20], p[21], p[22], p[23], p[24], p[26], nullptr, batch, pooled, 256, NNODES);

    // --- final linear on mean-pooled JK-concat
    final_kernel<<<NGRAPHS, 128, 0, stream>>>(pooled, batch, lin_W, lin_b,
                                              (float*)d_out, NNODES);
}